// Round 16
// baseline (178.640 us; speedup 1.0000x reference)
//
#include <hip/hip_runtime.h>
#include <hip/hip_bf16.h>
#include <cstdint>
#include <cstddef>

typedef __bf16 bf16;
typedef bf16 bf16x4 __attribute__((ext_vector_type(4)));
typedef bf16 bf16x8 __attribute__((ext_vector_type(8)));
typedef float f32x4 __attribute__((ext_vector_type(4)));

#define MFMA_BF16(a,b,c) __builtin_amdgcn_mfma_f32_16x16x32_bf16((a),(b),(c),0,0,0)

typedef __attribute__((address_space(1))) const void gvoid;
typedef __attribute__((address_space(3))) void svoid;
__device__ __forceinline__ void gload16(const bf16* g, bf16* l){
  __builtin_amdgcn_global_load_lds((gvoid*)g, (svoid*)l, 16, 0, 0);
}

// HEAD_COUNTS = [8,6,4,4,6,4] -> boundaries 8,14,18,22,28,32
__device__ __forceinline__ int head_group(int h){
  return (h<8)?0:(h<14)?1:(h<18)?2:(h<22)?3:(h<28)?4:5;
}

// ---------------- fused f32->bf16 convert (5 tensors) + RoPE tables in one launch ----------
struct CvtArgs { const float* src[5]; bf16* dst[5]; };
__global__ __launch_bounds__(256) void cvt_rope_kernel(CvtArgs a, int n,
                                                       float* __restrict__ cosT,
                                                       float* __restrict__ sinT){
  const int z = blockIdx.y;
  if (z == 5){                              // RoPE cos/sin tables: [T][32] f32
    if (blockIdx.x >= 256) return;
    const int t = blockIdx.x*8 + (threadIdx.x>>5);
    const int i = threadIdx.x&31;
    float invf = powf(10000.0f, -((float)i)/32.0f);
    float ang = (float)t * invf;
    cosT[t*32+i] = cosf(ang);
    sinT[t*32+i] = sinf(ang);
    return;
  }
  const float* __restrict__ in = a.src[z];
  bf16* __restrict__ out = a.dst[z];
  int i = (blockIdx.x*256 + threadIdx.x)*8;
  if (i >= n) return;
  const float4* p = (const float4*)(in + i);
  float4 va = p[0], vb = p[1];
  bf16x8 o;
  o[0]=(bf16)va.x; o[1]=(bf16)va.y; o[2]=(bf16)va.z; o[3]=(bf16)va.w;
  o[4]=(bf16)vb.x; o[5]=(bf16)vb.y; o[6]=(bf16)vb.z; o[7]=(bf16)vb.w;
  *(bf16x8*)(out+i) = o;
}

// ---------------- GEMM core: acc = A[M,K] * B[N,K]^T, 128x128 tile, BK=64 ----------------
// m97 staging via global_load_lds; [row][64] LDS with XOR col-slot swizzle
// (LDS[r][s] = src col-block s^(r&7); write: pre-swizzled source, linear dst;
// read: slot = c ^ (l16&7)). 32 iterations, 2 barriers each, 32 MFMA between.
__device__ __forceinline__ void gemm_core(const bf16* __restrict__ A,
                                          const bf16* __restrict__ B,
                                          int row0, int col0,
                                          f32x4 (&acc)[4][4]){
  __shared__ bf16 As[128*64];
  __shared__ bf16 Bs[128*64];
  const int tid  = threadIdx.x;
  const int wave = tid>>6, lane = tid&63;
  const int l16  = lane&15, lg = lane>>4;
  const int wr   = wave>>1, wc = wave&1;

  // staging: one gload16 covers 8 rows x 64 cols; lane -> row +(lane>>3),
  // LDS col-slot lane&7, source col-block (lane&7)^(lane>>3)  (row&7 == lane>>3)
  const int srow = lane>>3;
  const int scol = ((lane&7) ^ srow)*8;
  const bf16* Ag0 = A + (size_t)(row0 + wave*32      + srow)*2048 + scol;
  const bf16* Ag1 = A + (size_t)(row0 + wave*32 +  8 + srow)*2048 + scol;
  const bf16* Ag2 = A + (size_t)(row0 + wave*32 + 16 + srow)*2048 + scol;
  const bf16* Ag3 = A + (size_t)(row0 + wave*32 + 24 + srow)*2048 + scol;
  const bf16* Bg0 = B + (size_t)(col0 + wave*32      + srow)*2048 + scol;
  const bf16* Bg1 = B + (size_t)(col0 + wave*32 +  8 + srow)*2048 + scol;
  const bf16* Bg2 = B + (size_t)(col0 + wave*32 + 16 + srow)*2048 + scol;
  const bf16* Bg3 = B + (size_t)(col0 + wave*32 + 24 + srow)*2048 + scol;
  bf16* Ad0 = As + (wave*32     )*64;
  bf16* Ad1 = As + (wave*32 +  8)*64;
  bf16* Ad2 = As + (wave*32 + 16)*64;
  bf16* Ad3 = As + (wave*32 + 24)*64;
  bf16* Bd0 = Bs + (wave*32     )*64;
  bf16* Bd1 = Bs + (wave*32 +  8)*64;
  bf16* Bd2 = Bs + (wave*32 + 16)*64;
  bf16* Bd3 = Bs + (wave*32 + 24)*64;

  #pragma unroll
  for (int m=0;m<4;++m)
    #pragma unroll
    for (int n=0;n<4;++n)
      #pragma unroll
      for (int r=0;r<4;++r) acc[m][n][r] = 0.f;

  // fragment read offsets (elems): row*64 + slot*8
  int rA0[4], rA1[4], rB0[4], rB1[4];
  #pragma unroll
  for (int i=0;i<4;++i){
    const int ra = wr*64 + i*16 + l16;
    const int rb = wc*64 + i*16 + l16;
    rA0[i] = ra*64 + (((lg  ) ^ (l16&7))<<3);
    rA1[i] = ra*64 + (((4+lg) ^ (l16&7))<<3);
    rB0[i] = rb*64 + (((lg  ) ^ (l16&7))<<3);
    rB1[i] = rb*64 + (((4+lg) ^ (l16&7))<<3);
  }

  for (int kt=0; kt<32; ++kt){
    const int ko = kt*64;
    gload16(Ag0 + ko, Ad0);
    gload16(Ag1 + ko, Ad1);
    gload16(Ag2 + ko, Ad2);
    gload16(Ag3 + ko, Ad3);
    gload16(Bg0 + ko, Bd0);
    gload16(Bg1 + ko, Bd1);
    gload16(Bg2 + ko, Bd2);
    gload16(Bg3 + ko, Bd3);
    __syncthreads();                       // drain DMA -> tile visible
    bf16x8 a0[4], a1[4], b0[4], b1[4];
    #pragma unroll
    for (int i=0;i<4;++i){
      a0[i] = *(const bf16x8*)&As[rA0[i]];
      a1[i] = *(const bf16x8*)&As[rA1[i]];
      b0[i] = *(const bf16x8*)&Bs[rB0[i]];
      b1[i] = *(const bf16x8*)&Bs[rB1[i]];
    }
    #pragma unroll
    for (int m=0;m<4;++m)
      #pragma unroll
      for (int n=0;n<4;++n){
        acc[m][n] = MFMA_BF16(a0[m], b0[n], acc[m][n]);
        acc[m][n] = MFMA_BF16(a1[m], b1[n], acc[m][n]);
      }
    __syncthreads();                       // all reads done before next overwrite
  }
}

// ---------------- QKV GEMM with fused RoPE / relayout / V-transpose epilogues ----------------
__global__ __launch_bounds__(256) void gemm_qkv_kernel(
    const bf16* __restrict__ A,
    const bf16* __restrict__ B0, const bf16* __restrict__ B1, const bf16* __restrict__ B2,
    bf16* __restrict__ Qs, bf16* __restrict__ Ks, bf16* __restrict__ Vt,
    const float* __restrict__ cosT, const float* __restrict__ sinT,
    const float* __restrict__ mw, const float* __restrict__ ts){
  const int z = blockIdx.z;
  const bf16* B = (z==0)?B0:((z==1)?B1:B2);
  const int row0 = blockIdx.y*128, col0 = blockIdx.x*128;

  f32x4 acc[4][4];
  gemm_core(A, B, row0, col0, acc);

  const int tid  = threadIdx.x;
  const int wave = tid>>6, lane = tid&63;
  const int l16  = lane&15, lg = lane>>4;
  const int wr   = wave>>1, wc = wave&1;
  const int h    = (col0 + wc*64) >> 6;      // wave's 64-col span = one head

  if (z == 2){
    // V-transpose epilogue: acc[m][n][0..3] = 4 consecutive t -> one 8B store
    #pragma unroll
    for (int n=0;n<4;++n){
      const int d = n*16 + l16;
      #pragma unroll
      for (int m=0;m<4;++m){
        const int t0 = row0 + wr*64 + m*16 + lg*4;
        bf16x4 v;
        #pragma unroll
        for (int r=0;r<4;++r) v[r] = (bf16)acc[m][n][r];
        *(bf16x4*)&Vt[((size_t)h*64 + d)*2048 + t0] = v;
      }
    }
  } else {
    const float sc = (z==0) ? 0.125f*ts[h]*mw[head_group(h)] : 1.0f;
    bf16* Out = (z==0) ? Qs : Ks;
    #pragma unroll
    for (int m=0;m<4;++m){
      #pragma unroll
      for (int r=0;r<4;++r){
        const int t = row0 + wr*64 + m*16 + lg*4 + r;
        const float* ct = cosT + t*32;
        const float* st = sinT + t*32;
        bf16* dst = Out + ((size_t)h*2048 + t)*64;
        #pragma unroll
        for (int n=0;n<2;++n){
          const int i = n*16 + l16;
          const float c = ct[i], s = st[i];
          const float a1 = acc[m][n][r], a2 = acc[m][n+2][r];
          dst[i]    = (bf16)((a1*c - a2*s)*sc);
          dst[i+32] = (bf16)((a2*c + a1*s)*sc);
        }
      }
    }
  }
}

// ---------------- output GEMM: 128x64 tile, BK=64, same swizzle (2 blocks/CU) ----------------
__global__ __launch_bounds__(256) void gemm_out_kernel(
    const bf16* __restrict__ A, const bf16* __restrict__ B, float* __restrict__ C){
  __shared__ bf16 As[128*64];
  __shared__ bf16 Bs[64*64];
  const int row0 = blockIdx.y*128, col0 = blockIdx.x*64;
  const int tid  = threadIdx.x;
  const int wave = tid>>6, lane = tid&63;
  const int l16  = lane&15, lg = lane>>4;
  const int wr   = wave>>1, wc = wave&1;

  const int srow = lane>>3;
  const int scol = ((lane&7) ^ srow)*8;
  const bf16* Ag0 = A + (size_t)(row0 + wave*32      + srow)*2048 + scol;
  const bf16* Ag1 = A + (size_t)(row0 + wave*32 +  8 + srow)*2048 + scol;
  const bf16* Ag2 = A + (size_t)(row0 + wave*32 + 16 + srow)*2048 + scol;
  const bf16* Ag3 = A + (size_t)(row0 + wave*32 + 24 + srow)*2048 + scol;
  const bf16* Bg0 = B + (size_t)(col0 + wave*16      + srow)*2048 + scol;
  const bf16* Bg1 = B + (size_t)(col0 + wave*16 +  8 + srow)*2048 + scol;
  bf16* Ad0 = As + (wave*32     )*64;
  bf16* Ad1 = As + (wave*32 +  8)*64;
  bf16* Ad2 = As + (wave*32 + 16)*64;
  bf16* Ad3 = As + (wave*32 + 24)*64;
  bf16* Bd0 = Bs + (wave*16     )*64;
  bf16* Bd1 = Bs + (wave*16 +  8)*64;

  f32x4 acc[4][2];
  #pragma unroll
  for (int m=0;m<4;++m)
    #pragma unroll
    for (int n=0;n<2;++n)
      #pragma unroll
      for (int r=0;r<4;++r) acc[m][n][r] = 0.f;

  int rA0[4], rA1[4], rB0[2], rB1[2];
  #pragma unroll
  for (int i=0;i<4;++i){
    const int ra = wr*64 + i*16 + l16;
    rA0[i] = ra*64 + (((lg  ) ^ (l16&7))<<3);
    rA1[i] = ra*64 + (((4+lg) ^ (l16&7))<<3);
  }
  #pragma unroll
  for (int i=0;i<2;++i){
    const int rb = wc*32 + i*16 + l16;
    rB0[i] = rb*64 + (((lg  ) ^ (l16&7))<<3);
    rB1[i] = rb*64 + (((4+lg) ^ (l16&7))<<3);
  }

  for (int kt=0; kt<32; ++kt){
    const int ko = kt*64;
    gload16(Ag0 + ko, Ad0);
    gload16(Ag1 + ko, Ad1);
    gload16(Ag2 + ko, Ad2);
    gload16(Ag3 + ko, Ad3);
    gload16(Bg0 + ko, Bd0);
    gload16(Bg1 + ko, Bd1);
    __syncthreads();
    bf16x8 a0[4], a1[4], b0[2], b1[2];
    #pragma unroll
    for (int i=0;i<4;++i){
      a0[i] = *(const bf16x8*)&As[rA0[i]];
      a1[i] = *(const bf16x8*)&As[rA1[i]];
    }
    #pragma unroll
    for (int i=0;i<2;++i){
      b0[i] = *(const bf16x8*)&Bs[rB0[i]];
      b1[i] = *(const bf16x8*)&Bs[rB1[i]];
    }
    #pragma unroll
    for (int m=0;m<4;++m)
      #pragma unroll
      for (int n=0;n<2;++n){
        acc[m][n] = MFMA_BF16(a0[m], b0[n], acc[m][n]);
        acc[m][n] = MFMA_BF16(a1[m], b1[n], acc[m][n]);
      }
    __syncthreads();
  }

  #pragma unroll
  for (int m=0;m<4;++m)
    #pragma unroll
    for (int n=0;n<2;++n)
      #pragma unroll
      for (int r=0;r<4;++r){
        size_t idx = (size_t)(row0 + wr*64 + m*16 + lg*4 + r)*2048
                   + col0 + wc*32 + n*16 + l16;
        C[idx] = acc[m][n][r];
      }
}

// ---------------- fused causal attention (r15 verbatim: best measured) ----------------
__global__ __launch_bounds__(512) void attn_kernel(
    const bf16* __restrict__ Qs, const bf16* __restrict__ Ks,
    const bf16* __restrict__ Vt, const float* __restrict__ biasf,
    const float* __restrict__ mw, bf16* __restrict__ attout){
  const int n  = blockIdx.x;                       // 0..511
  const int h  = ((n&7)<<2) | ((n>>3)&3);          // 0..31, XCD-grouped
  const int qt = (n&256) ? ((n>>5)&7) : 15-((n>>5)&7);
  const int tid = threadIdx.x, wid = tid>>6, lane = tid&63;
  const int l16 = lane&15, lg = lane>>4;
  const float w_h = mw[head_group(h)];
  const int qbase = qt*128 + wid*16;
  const int qg0 = qbase + lg*4;                    // +r = this lane's q rows
  const int nkt = 2*qt + 2;

  __shared__ bf16 Kl[2][4096];
  __shared__ bf16 Vl[2][4096];
  __shared__ bf16 plds[8][16][72];

  // staging: 512 threads, one b128 per tensor per tile
  const int srow = tid>>3, ssub = tid&7;
  const bf16* Kg = Ks + (size_t)h*2048*64 + srow*64 + ssub*8;   // + k0*64
  const bf16* Vg = Vt + ((size_t)h*64 + srow)*2048 + ssub*8;    // + k0
  const int wsw = srow*64 + ((ssub ^ (srow&7))<<3);

  // Q fragments (registers, whole kernel)
  const bf16* Qp = Qs + ((size_t)h*2048 + qbase + l16)*64 + lg*8;
  bf16x8 qf0 = *(const bf16x8*)Qp;
  bf16x8 qf1 = *(const bf16x8*)(Qp + 32);

  const float* Bg = biasf + (size_t)qg0*2048;      // rows qg0..qg0+3

  f32x4 O[4];
  float l[4] = {0.f,0.f,0.f,0.f};
  #pragma unroll
  for (int c=0;c<4;++c)
    #pragma unroll
    for (int r=0;r<4;++r) O[c][r] = 0.f;

  int rK0[4], rK1[4];
  #pragma unroll
  for (int c=0;c<4;++c){
    const int row = c*16 + l16;
    rK0[c] = row*64 + (((lg  ) ^ (row&7))<<3);
    rK1[c] = row*64 + (((4+lg) ^ (row&7))<<3);
  }

  // bias for current tile, prefetched one iteration ahead (w_h folded in)
  float bc[4][4];
  #pragma unroll
  for (int c=0;c<4;++c)
    #pragma unroll
    for (int r=0;r<4;++r)
      bc[c][r] = w_h * Bg[(size_t)r*2048 + c*16 + l16];

  // prologue: stage tile 0
  {
    bf16x8 k0v = *(const bf16x8*)Kg;
    bf16x8 v0v = *(const bf16x8*)Vg;
    *(bf16x8*)&Kl[0][wsw] = k0v;
    *(bf16x8*)&Vl[0][wsw] = v0v;
  }
  __syncthreads();

  int cur = 0;
  for (int kt=0; kt<nkt; ++kt){
    const int k0 = kt*64;
    const bool more = (kt+1 < nkt);
    bf16x8 kA, vA;
    float bn[4][4];
    if (more){
      kA = *(const bf16x8*)(Kg + (size_t)(k0+64)*64);
      vA = *(const bf16x8*)(Vg + (k0+64));
      #pragma unroll
      for (int c=0;c<4;++c)
        #pragma unroll
        for (int r=0;r<4;++r)
          bn[c][r] = w_h * Bg[(size_t)r*2048 + (k0+64) + c*16 + l16];
    }

    if (k0 <= qbase + 15){                 // wave-uniform skip of fully-masked tiles
      f32x4 S[4];
      #pragma unroll
      for (int c=0;c<4;++c)
        #pragma unroll
        for (int r=0;r<4;++r) S[c][r] = bc[c][r];

      __builtin_amdgcn_s_setprio(1);
      #pragma unroll
      for (int c=0;c<4;++c){
        bf16x8 kf0 = *(const bf16x8*)&Kl[cur][rK0[c]];
        bf16x8 kf1 = *(const bf16x8*)&Kl[cur][rK1[c]];
        S[c] = MFMA_BF16(qf0, kf0, S[c]);
        S[c] = MFMA_BF16(qf1, kf1, S[c]);
      }
      __builtin_amdgcn_s_setprio(0);

      #pragma unroll
      for (int c=0;c<4;++c){
        const int kg = k0 + c*16 + l16;
        #pragma unroll
        for (int r=0;r<4;++r){
          float s = S[c][r];
          if (kg > qg0+r) s = -1e30f;
          const float p = __expf(s - 4.0f);
          S[c][r] = p; l[r] += p;
        }
      }

      #pragma unroll
      for (int c=0;c<4;++c)
        #pragma unroll
        for (int r=0;r<4;++r)
          plds[wid][lg*4+r][c*16+l16] = (bf16)S[c][r];
      bf16x8 pf0 = *(const bf16x8*)&plds[wid][l16][lg*8];
      bf16x8 pf1 = *(const bf16x8*)&plds[wid][l16][lg*8+32];

      __builtin_amdgcn_s_setprio(1);
      #pragma unroll
      for (int c=0;c<4;++c){
        bf16x8 vf0 = *(const bf16x8*)&Vl[cur][rK0[c]];
        bf16x8 vf1 = *(const bf16x8*)&Vl[cur][rK1[c]];
        O[c] = MFMA_BF16(pf0, vf0, O[c]);
        O[c] = MFMA_BF16(pf1, vf1, O[c]);
      }
      __builtin_amdgcn_s_setprio(0);
    }

    if (more){
      *(bf16x8*)&Kl[cur^1][wsw] = kA;
      *(bf16x8*)&Vl[cur^1][wsw] = vA;
      #pragma unroll
      for (int c=0;c<4;++c)
        #pragma unroll
        for (int r=0;r<4;++r) bc[c][r] = bn[c][r];
    }
    __syncthreads();
    cur ^= (int)more;
  }

  #pragma unroll
  for (int r=0;r<4;++r){
    float v = l[r];
    v += __shfl_xor(v,1);
    v += __shfl_xor(v,2);
    v += __shfl_xor(v,4);
    v += __shfl_xor(v,8);
    l[r] = 1.0f / v;
  }
  #pragma unroll
  for (int c=0;c<4;++c)
    #pragma unroll
    for (int r=0;r<4;++r)
      attout[(size_t)(qg0+r)*2048 + h*64 + c*16 + l16] = (bf16)(O[c][r]*l[r]);
}

// ---------------- launcher ----------------
extern "C" void kernel_launch(void* const* d_in, const int* in_sizes, int n_in,
                              void* d_out, int out_size, void* d_ws, size_t ws_size,
                              hipStream_t stream){
  const float* x    = (const float*)d_in[0];
  const float* bias = (const float*)d_in[2];
  const float* mw   = (const float*)d_in[3];
  const float* Wq   = (const float*)d_in[4];
  const float* Wk   = (const float*)d_in[5];
  const float* Wv   = (const float*)d_in[6];
  const float* Wo   = (const float*)d_in[7];
  const float* ts   = (const float*)d_in[8];
  float* out = (float*)d_out;

  const size_t SZ = (size_t)2048*2048;
  bf16* base = (bf16*)d_ws;
  bf16* xb   = base;
  bf16* Wqb  = base + 1*SZ;
  bf16* Wkb  = base + 2*SZ;
  bf16* Wvb  = base + 3*SZ;
  bf16* Wob  = base + 4*SZ;
  bf16* Qsb  = base + 5*SZ;
  bf16* Ksb  = base + 6*SZ;
  bf16* Vtb  = base + 7*SZ;
  bf16* att  = base + 8*SZ;
  float* cosT = (float*)(base + 9*SZ);
  float* sinT = cosT + 2048*32;

  CvtArgs ca;
  ca.src[0]=x;  ca.src[1]=Wq;  ca.src[2]=Wk;  ca.src[3]=Wv;  ca.src[4]=Wo;
  ca.dst[0]=xb; ca.dst[1]=Wqb; ca.dst[2]=Wkb; ca.dst[3]=Wvb; ca.dst[4]=Wob;
  const int nb = (int)(SZ/8/256);
  cvt_rope_kernel<<<dim3(nb,6),256,0,stream>>>(ca, (int)SZ, cosT, sinT);
  gemm_qkv_kernel<<<dim3(16,16,3),256,0,stream>>>(xb, Wqb,Wkb,Wvb,
                                                  Qsb,Ksb,Vtb, cosT,sinT, mw,ts);
  attn_kernel<<<512,512,0,stream>>>(Qsb,Ksb,Vtb,bias,mw,att);
  gemm_out_kernel<<<dim3(32,16),256,0,stream>>>(att, Wob, out);
}

// Round 17
// 165.784 us; speedup vs baseline: 1.0775x; 1.0775x over previous
//
#include <hip/hip_runtime.h>
#include <hip/hip_bf16.h>
#include <cstdint>
#include <cstddef>

typedef __bf16 bf16;
typedef bf16 bf16x4 __attribute__((ext_vector_type(4)));
typedef bf16 bf16x8 __attribute__((ext_vector_type(8)));
typedef float f32x4 __attribute__((ext_vector_type(4)));

#define MFMA_BF16(a,b,c) __builtin_amdgcn_mfma_f32_16x16x32_bf16((a),(b),(c),0,0,0)

typedef __attribute__((address_space(1))) const void gvoid;
typedef __attribute__((address_space(3))) void svoid;
__device__ __forceinline__ void gload16(const bf16* g, bf16* l){
  __builtin_amdgcn_global_load_lds((gvoid*)g, (svoid*)l, 16, 0, 0);
}

// HEAD_COUNTS = [8,6,4,4,6,4] -> boundaries 8,14,18,22,28,32
__device__ __forceinline__ int head_group(int h){
  return (h<8)?0:(h<14)?1:(h<18)?2:(h<22)?3:(h<28)?4:5;
}

// ---------------- fused f32->bf16 convert (5 tensors) + RoPE tables in one launch ----------
struct CvtArgs { const float* src[5]; bf16* dst[5]; };
__global__ __launch_bounds__(256) void cvt_rope_kernel(CvtArgs a, int n,
                                                       float* __restrict__ cosT,
                                                       float* __restrict__ sinT){
  const int z = blockIdx.y;
  if (z == 5){                              // RoPE cos/sin tables: [T][32] f32
    if (blockIdx.x >= 256) return;
    const int t = blockIdx.x*8 + (threadIdx.x>>5);
    const int i = threadIdx.x&31;
    float invf = powf(10000.0f, -((float)i)/32.0f);
    float ang = (float)t * invf;
    cosT[t*32+i] = cosf(ang);
    sinT[t*32+i] = sinf(ang);
    return;
  }
  const float* __restrict__ in = a.src[z];
  bf16* __restrict__ out = a.dst[z];
  int i = (blockIdx.x*256 + threadIdx.x)*8;
  if (i >= n) return;
  const float4* p = (const float4*)(in + i);
  float4 va = p[0], vb = p[1];
  bf16x8 o;
  o[0]=(bf16)va.x; o[1]=(bf16)va.y; o[2]=(bf16)va.z; o[3]=(bf16)va.w;
  o[4]=(bf16)vb.x; o[5]=(bf16)vb.y; o[6]=(bf16)vb.z; o[7]=(bf16)vb.w;
  *(bf16x8*)(out+i) = o;
}

// ---------------- GEMM core: acc = A[M,K] * B[N,K]^T, 128x128 tile ----------------
// m97 structure: BK=32, linear LDS, global_load_lds width=16, 2 barriers/K-step.
// NOTE (r16 lesson): BK=64 + XOR swizzle removes bank conflicts but loses more to
// L2 reuse (+70% FETCH) and occupancy (28->15%) than it gains. BK=32 is the optimum.
__device__ __forceinline__ void gemm_core(const bf16* __restrict__ A,
                                          const bf16* __restrict__ B,
                                          int row0, int col0,
                                          f32x4 (&acc)[4][4]){
  __shared__ bf16 As[128*32];
  __shared__ bf16 Bs[128*32];
  const int tid  = threadIdx.x;
  const int wave = tid>>6, lane = tid&63;
  const int l16  = lane&15, lg = lane>>4;
  const int wr   = wave>>1, wc = wave&1;

  const bf16* Ag0 = A + (size_t)(row0 + wave*32      + (lane>>2))*2048 + (lane&3)*8;
  const bf16* Ag1 = A + (size_t)(row0 + wave*32 + 16 + (lane>>2))*2048 + (lane&3)*8;
  const bf16* Bg0 = B + (size_t)(col0 + wave*32      + (lane>>2))*2048 + (lane&3)*8;
  const bf16* Bg1 = B + (size_t)(col0 + wave*32 + 16 + (lane>>2))*2048 + (lane&3)*8;
  bf16* AsB0 = As + (wave*32     )*32;
  bf16* AsB1 = As + (wave*32 + 16)*32;
  bf16* BsB0 = Bs + (wave*32     )*32;
  bf16* BsB1 = Bs + (wave*32 + 16)*32;

  #pragma unroll
  for (int m=0;m<4;++m)
    #pragma unroll
    for (int n=0;n<4;++n)
      #pragma unroll
      for (int r=0;r<4;++r) acc[m][n][r] = 0.f;

  for (int kt=0; kt<64; ++kt){
    const int ko = kt*32;
    gload16(Ag0 + ko, AsB0);
    gload16(Ag1 + ko, AsB1);
    gload16(Bg0 + ko, BsB0);
    gload16(Bg1 + ko, BsB1);
    __syncthreads();
    bf16x8 af[4], bfr[4];
    #pragma unroll
    for (int m=0;m<4;++m) af[m]  = *(const bf16x8*)&As[(wr*64+m*16+l16)*32 + lg*8];
    #pragma unroll
    for (int n=0;n<4;++n) bfr[n] = *(const bf16x8*)&Bs[(wc*64+n*16+l16)*32 + lg*8];
    #pragma unroll
    for (int m=0;m<4;++m)
      #pragma unroll
      for (int n=0;n<4;++n)
        acc[m][n] = MFMA_BF16(af[m], bfr[n], acc[m][n]);
    __syncthreads();
  }
}

// ---------------- QKV GEMM with fused RoPE / relayout / V-transpose epilogues ----------------
__global__ __launch_bounds__(256) void gemm_qkv_kernel(
    const bf16* __restrict__ A,
    const bf16* __restrict__ B0, const bf16* __restrict__ B1, const bf16* __restrict__ B2,
    bf16* __restrict__ Qs, bf16* __restrict__ Ks, bf16* __restrict__ Vt,
    const float* __restrict__ cosT, const float* __restrict__ sinT,
    const float* __restrict__ mw, const float* __restrict__ ts){
  const int z = blockIdx.z;
  const bf16* B = (z==0)?B0:((z==1)?B1:B2);
  const int row0 = blockIdx.y*128, col0 = blockIdx.x*128;

  f32x4 acc[4][4];
  gemm_core(A, B, row0, col0, acc);

  const int tid  = threadIdx.x;
  const int wave = tid>>6, lane = tid&63;
  const int l16  = lane&15, lg = lane>>4;
  const int wr   = wave>>1, wc = wave&1;
  const int h    = (col0 + wc*64) >> 6;      // wave's 64-col span = one head

  if (z == 2){
    // V-transpose epilogue: acc[m][n][0..3] = 4 consecutive t -> one 8B store
    #pragma unroll
    for (int n=0;n<4;++n){
      const int d = n*16 + l16;
      #pragma unroll
      for (int m=0;m<4;++m){
        const int t0 = row0 + wr*64 + m*16 + lg*4;
        bf16x4 v;
        #pragma unroll
        for (int r=0;r<4;++r) v[r] = (bf16)acc[m][n][r];
        *(bf16x4*)&Vt[((size_t)h*64 + d)*2048 + t0] = v;
      }
    }
  } else {
    const float sc = (z==0) ? 0.125f*ts[h]*mw[head_group(h)] : 1.0f;
    bf16* Out = (z==0) ? Qs : Ks;
    #pragma unroll
    for (int m=0;m<4;++m){
      #pragma unroll
      for (int r=0;r<4;++r){
        const int t = row0 + wr*64 + m*16 + lg*4 + r;
        const float* ct = cosT + t*32;
        const float* st = sinT + t*32;
        bf16* dst = Out + ((size_t)h*2048 + t)*64;
        #pragma unroll
        for (int n=0;n<2;++n){
          const int i = n*16 + l16;
          const float c = ct[i], s = st[i];
          const float a1 = acc[m][n][r], a2 = acc[m][n+2][r];
          dst[i]    = (bf16)((a1*c - a2*s)*sc);
          dst[i+32] = (bf16)((a2*c + a1*s)*sc);
        }
      }
    }
  }
}

// ---------------- output GEMM: 128x64 tile (512 blocks -> 2 blocks/CU) ----------------
__global__ __launch_bounds__(256) void gemm_out_kernel(
    const bf16* __restrict__ A, const bf16* __restrict__ B, float* __restrict__ C){
  __shared__ bf16 As[128*32];
  __shared__ bf16 Bs[64*32];
  const int row0 = blockIdx.y*128, col0 = blockIdx.x*64;
  const int tid  = threadIdx.x;
  const int wave = tid>>6, lane = tid&63;
  const int l16  = lane&15, lg = lane>>4;
  const int wr   = wave>>1, wc = wave&1;

  const bf16* Ag0 = A + (size_t)(row0 + wave*32      + (lane>>2))*2048 + (lane&3)*8;
  const bf16* Ag1 = A + (size_t)(row0 + wave*32 + 16 + (lane>>2))*2048 + (lane&3)*8;
  const bf16* Bg0 = B + (size_t)(col0 + wave*16      + (lane>>2))*2048 + (lane&3)*8;
  bf16* AsB0 = As + (wave*32     )*32;
  bf16* AsB1 = As + (wave*32 + 16)*32;
  bf16* BsB0 = Bs + (wave*16     )*32;

  f32x4 acc[4][2];
  #pragma unroll
  for (int m=0;m<4;++m)
    #pragma unroll
    for (int n=0;n<2;++n)
      #pragma unroll
      for (int r=0;r<4;++r) acc[m][n][r] = 0.f;

  for (int kt=0; kt<64; ++kt){
    const int ko = kt*32;
    gload16(Ag0 + ko, AsB0);
    gload16(Ag1 + ko, AsB1);
    gload16(Bg0 + ko, BsB0);
    __syncthreads();
    bf16x8 af[4], bfr[2];
    #pragma unroll
    for (int m=0;m<4;++m) af[m]  = *(const bf16x8*)&As[(wr*64+m*16+l16)*32 + lg*8];
    #pragma unroll
    for (int n=0;n<2;++n) bfr[n] = *(const bf16x8*)&Bs[(wc*32+n*16+l16)*32 + lg*8];
    #pragma unroll
    for (int m=0;m<4;++m)
      #pragma unroll
      for (int n=0;n<2;++n)
        acc[m][n] = MFMA_BF16(af[m], bfr[n], acc[m][n]);
    __syncthreads();
  }

  #pragma unroll
  for (int m=0;m<4;++m)
    #pragma unroll
    for (int n=0;n<2;++n)
      #pragma unroll
      for (int r=0;r<4;++r){
        size_t idx = (size_t)(row0 + wr*64 + m*16 + lg*4 + r)*2048
                   + col0 + wc*32 + n*16 + l16;
        C[idx] = acc[m][n][r];
      }
}

// ---------------- fused causal attention (best measured: r8 loop + f32 bias direct
// with 1-iter prefetch + XCD-grouped heads + complementary-qt pairing) ----------------
__global__ __launch_bounds__(512) void attn_kernel(
    const bf16* __restrict__ Qs, const bf16* __restrict__ Ks,
    const bf16* __restrict__ Vt, const float* __restrict__ biasf,
    const float* __restrict__ mw, bf16* __restrict__ attout){
  const int n  = blockIdx.x;                       // 0..511
  const int h  = ((n&7)<<2) | ((n>>3)&3);          // 0..31, XCD-grouped
  const int qt = (n&256) ? ((n>>5)&7) : 15-((n>>5)&7);
  const int tid = threadIdx.x, wid = tid>>6, lane = tid&63;
  const int l16 = lane&15, lg = lane>>4;
  const float w_h = mw[head_group(h)];
  const int qbase = qt*128 + wid*16;
  const int qg0 = qbase + lg*4;                    // +r = this lane's q rows
  const int nkt = 2*qt + 2;

  __shared__ bf16 Kl[2][4096];
  __shared__ bf16 Vl[2][4096];
  __shared__ bf16 plds[8][16][72];

  // staging: 512 threads, one b128 per tensor per tile
  const int srow = tid>>3, ssub = tid&7;
  const bf16* Kg = Ks + (size_t)h*2048*64 + srow*64 + ssub*8;   // + k0*64
  const bf16* Vg = Vt + ((size_t)h*64 + srow)*2048 + ssub*8;    // + k0
  const int wsw = srow*64 + ((ssub ^ (srow&7))<<3);

  // Q fragments (registers, whole kernel)
  const bf16* Qp = Qs + ((size_t)h*2048 + qbase + l16)*64 + lg*8;
  bf16x8 qf0 = *(const bf16x8*)Qp;
  bf16x8 qf1 = *(const bf16x8*)(Qp + 32);

  const float* Bg = biasf + (size_t)qg0*2048;      // rows qg0..qg0+3

  f32x4 O[4];
  float l[4] = {0.f,0.f,0.f,0.f};
  #pragma unroll
  for (int c=0;c<4;++c)
    #pragma unroll
    for (int r=0;r<4;++r) O[c][r] = 0.f;

  int rK0[4], rK1[4];
  #pragma unroll
  for (int c=0;c<4;++c){
    const int row = c*16 + l16;
    rK0[c] = row*64 + (((lg  ) ^ (row&7))<<3);
    rK1[c] = row*64 + (((4+lg) ^ (row&7))<<3);
  }

  // bias for current tile, prefetched one iteration ahead (w_h folded in)
  float bc[4][4];
  #pragma unroll
  for (int c=0;c<4;++c)
    #pragma unroll
    for (int r=0;r<4;++r)
      bc[c][r] = w_h * Bg[(size_t)r*2048 + c*16 + l16];

  // prologue: stage tile 0
  {
    bf16x8 k0v = *(const bf16x8*)Kg;
    bf16x8 v0v = *(const bf16x8*)Vg;
    *(bf16x8*)&Kl[0][wsw] = k0v;
    *(bf16x8*)&Vl[0][wsw] = v0v;
  }
  __syncthreads();

  int cur = 0;
  for (int kt=0; kt<nkt; ++kt){
    const int k0 = kt*64;
    const bool more = (kt+1 < nkt);
    bf16x8 kA, vA;
    float bn[4][4];
    if (more){
      kA = *(const bf16x8*)(Kg + (size_t)(k0+64)*64);
      vA = *(const bf16x8*)(Vg + (k0+64));
      #pragma unroll
      for (int c=0;c<4;++c)
        #pragma unroll
        for (int r=0;r<4;++r)
          bn[c][r] = w_h * Bg[(size_t)r*2048 + (k0+64) + c*16 + l16];
    }

    if (k0 <= qbase + 15){                 // wave-uniform skip of fully-masked tiles
      f32x4 S[4];
      #pragma unroll
      for (int c=0;c<4;++c)
        #pragma unroll
        for (int r=0;r<4;++r) S[c][r] = bc[c][r];

      __builtin_amdgcn_s_setprio(1);
      #pragma unroll
      for (int c=0;c<4;++c){
        bf16x8 kf0 = *(const bf16x8*)&Kl[cur][rK0[c]];
        bf16x8 kf1 = *(const bf16x8*)&Kl[cur][rK1[c]];
        S[c] = MFMA_BF16(qf0, kf0, S[c]);
        S[c] = MFMA_BF16(qf1, kf1, S[c]);
      }
      __builtin_amdgcn_s_setprio(0);

      #pragma unroll
      for (int c=0;c<4;++c){
        const int kg = k0 + c*16 + l16;
        #pragma unroll
        for (int r=0;r<4;++r){
          float s = S[c][r];
          if (kg > qg0+r) s = -1e30f;
          const float p = __expf(s - 4.0f);
          S[c][r] = p; l[r] += p;
        }
      }

      #pragma unroll
      for (int c=0;c<4;++c)
        #pragma unroll
        for (int r=0;r<4;++r)
          plds[wid][lg*4+r][c*16+l16] = (bf16)S[c][r];
      bf16x8 pf0 = *(const bf16x8*)&plds[wid][l16][lg*8];
      bf16x8 pf1 = *(const bf16x8*)&plds[wid][l16][lg*8+32];

      __builtin_amdgcn_s_setprio(1);
      #pragma unroll
      for (int c=0;c<4;++c){
        bf16x8 vf0 = *(const bf16x8*)&Vl[cur][rK0[c]];
        bf16x8 vf1 = *(const bf16x8*)&Vl[cur][rK1[c]];
        O[c] = MFMA_BF16(pf0, vf0, O[c]);
        O[c] = MFMA_BF16(pf1, vf1, O[c]);
      }
      __builtin_amdgcn_s_setprio(0);
    }

    if (more){
      *(bf16x8*)&Kl[cur^1][wsw] = kA;
      *(bf16x8*)&Vl[cur^1][wsw] = vA;
      #pragma unroll
      for (int c=0;c<4;++c)
        #pragma unroll
        for (int r=0;r<4;++r) bc[c][r] = bn[c][r];
    }
    __syncthreads();
    cur ^= (int)more;
  }

  #pragma unroll
  for (int r=0;r<4;++r){
    float v = l[r];
    v += __shfl_xor(v,1);
    v += __shfl_xor(v,2);
    v += __shfl_xor(v,4);
    v += __shfl_xor(v,8);
    l[r] = 1.0f / v;
  }
  #pragma unroll
  for (int c=0;c<4;++c)
    #pragma unroll
    for (int r=0;r<4;++r)
      attout[(size_t)(qg0+r)*2048 + h*64 + c*16 + l16] = (bf16)(O[c][r]*l[r]);
}

// ---------------- launcher ----------------
extern "C" void kernel_launch(void* const* d_in, const int* in_sizes, int n_in,
                              void* d_out, int out_size, void* d_ws, size_t ws_size,
                              hipStream_t stream){
  const float* x    = (const float*)d_in[0];
  const float* bias = (const float*)d_in[2];
  const float* mw   = (const float*)d_in[3];
  const float* Wq   = (const float*)d_in[4];
  const float* Wk   = (const float*)d_in[5];
  const float* Wv   = (const float*)d_in[6];
  const float* Wo   = (const float*)d_in[7];
  const float* ts   = (const float*)d_in[8];
  float* out = (float*)d_out;

  const size_t SZ = (size_t)2048*2048;
  bf16* base = (bf16*)d_ws;
  bf16* xb   = base;
  bf16* Wqb  = base + 1*SZ;
  bf16* Wkb  = base + 2*SZ;
  bf16* Wvb  = base + 3*SZ;
  bf16* Wob  = base + 4*SZ;
  bf16* Qsb  = base + 5*SZ;
  bf16* Ksb  = base + 6*SZ;
  bf16* Vtb  = base + 7*SZ;
  bf16* att  = base + 8*SZ;
  float* cosT = (float*)(base + 9*SZ);
  float* sinT = cosT + 2048*32;

  CvtArgs ca;
  ca.src[0]=x;  ca.src[1]=Wq;  ca.src[2]=Wk;  ca.src[3]=Wv;  ca.src[4]=Wo;
  ca.dst[0]=xb; ca.dst[1]=Wqb; ca.dst[2]=Wkb; ca.dst[3]=Wvb; ca.dst[4]=Wob;
  const int nb = (int)(SZ/8/256);
  cvt_rope_kernel<<<dim3(nb,6),256,0,stream>>>(ca, (int)SZ, cosT, sinT);
  gemm_qkv_kernel<<<dim3(16,16,3),256,0,stream>>>(xb, Wqb,Wkb,Wvb,
                                                  Qsb,Ksb,Vtb, cosT,sinT, mw,ts);
  attn_kernel<<<512,512,0,stream>>>(Qsb,Ksb,Vtb,bias,mw,att);
  gemm_out_kernel<<<dim3(32,16),256,0,stream>>>(att, Wob, out);
}